// Round 8
// baseline (329.495 us; speedup 1.0000x reference)
//
#include <hip/hip_runtime.h>

typedef unsigned short u16;
typedef unsigned int u32;
typedef __bf16 bf16x8 __attribute__((ext_vector_type(8)));
typedef float f32x4 __attribute__((ext_vector_type(4)));

// Problem constants
constexpr int Bn = 32, Ln = 300, Dn = 256;
constexpr int Nn = Bn * Ln;          // 9600
constexpr int En = 4000, NNZn = 100000;
constexpr int DUn = 128, DFn = 384;
constexpr int PK = 512;              // packed row: [text 256 | img 256]
constexpr long NPl = (long)Nn * PK;  // 4915200
constexpr long EPl = (long)En * PK;  // 2048000
constexpr int PMAX = 1536;           // tail pair-list capacity

// prep_all block-segment start offsets
constexpr int SEG_WPROD = 0;                   // 512
constexpr int SEG_GIMG  = SEG_WPROD + 512;     // 9600
constexpr int SEG_W2T   = SEG_GIMG + 9600;     // 2048
constexpr int SEG_GTXT  = SEG_W2T + 2048;      // 2400
constexpr int SEG_W1T   = SEG_GTXT + 2400;     // 384
constexpr int SEG_WTAIL = SEG_W1T + 384;       // 2880 (Wq,Wk,Wv,Wo,Wd c-major bf16)
constexpr int SEG_W3C   = SEG_WTAIL + 2880;    // 1152 (W3 c-major bf16)
constexpr int SEG_PE    = SEG_W3C + 1152;      // 300
constexpr int SEG_CNT   = SEG_PE + 300;        // 391
constexpr int SEG_END   = SEG_CNT + 391;

__device__ __forceinline__ u16 f2bf(float f) {
    union { float f; u32 u; } x{f};
    u32 u = x.u;
    u32 r = (u + 0x7FFFu + ((u >> 16) & 1u)) >> 16;
    return (u16)r;
}
__device__ __forceinline__ float bf2f(u16 s) {
    union { u32 u; float f; } x{(u32)s << 16};
    return x.f;
}

// dot of 8 bf16 weights (contiguous) with 8 fp32 activations (LDS)
__device__ __forceinline__ float dot8(const u16* __restrict__ w, const float* __restrict__ x) {
    uint4 v = *(const uint4*)w;
    u16 h[8];
    *(uint4*)h = v;
    float s = 0.f;
#pragma unroll
    for (int j = 0; j < 8; j++) s += x[j] * bf2f(h[j]);
    return s;
}

// ---------------- fused prologue: all independent precompute ----------------
__global__ __launch_bounds__(256) void prep_all(
    float* __restrict__ pe_tab,
    const float* __restrict__ W1, u16* __restrict__ W1t,
    const float* __restrict__ W2, u16* __restrict__ W2t,
    const float* __restrict__ Wt, const float* __restrict__ bt,
    const float* __restrict__ Wi, const float* __restrict__ bi,
    u16* __restrict__ W12c, float* __restrict__ bias12, float* __restrict__ bias2w,
    const int* __restrict__ node_idx, const int* __restrict__ edge_idx,
    int* __restrict__ cnt_e, int* __restrict__ cnt_n,
    const float* __restrict__ text_table, const float* __restrict__ img_table,
    const int* __restrict__ rel, u16* __restrict__ Atx, u16* __restrict__ Aim,
    const float* __restrict__ Wq, const float* __restrict__ Wk,
    const float* __restrict__ Wv, const float* __restrict__ Wo,
    const float* __restrict__ Wd, u16* __restrict__ Wtail,
    const float* __restrict__ W3, u16* __restrict__ W3c) {
    int bid = blockIdx.x;
    int t = threadIdx.x;
    if (bid < SEG_GIMG) {  // wprod: W12 = W0 @ W1 per modality, C-MAJOR bf16 out
        int idx = bid * 256 + t;  // 131072
        int m = idx >> 16;
        int k = (idx >> 8) & 255;
        int n = idx & 255;
        const float* W0 = m ? Wi : Wt;
        const float* Wl1 = W0 + 65536;
        const float* b0 = m ? bi : bt;
        float acc = 0.f;
#pragma unroll 8
        for (int j = 0; j < 256; j++) acc += W0[k * 256 + j] * Wl1[j * 256 + n];
        W12c[((size_t)m << 16) + n * 256 + k] = f2bf(acc);
        if (k == 0) {
            float ba = 0.f;
            for (int j = 0; j < 256; j++) ba += b0[j] * Wl1[j * 256 + n];
            bias12[m * 256 + n] = ba + b0[256 + n];
            bias2w[m * 256 + n] = b0[256 + n];
        }
        return;
    }
    if (bid < SEG_W2T) {  // gather img row -> packed bf16 (streaming memcpy)
        int r = bid - SEG_GIMG;
        const float4* s4 = (const float4*)(img_table + (size_t)rel[r] * 2048);
        u16* drow = Aim + (size_t)r * 2048;
#pragma unroll
        for (int i = 0; i < 2; i++) {
            int e = i * 256 + t;  // 512 float4 per row
            float4 v = s4[e];
            u16 o[4] = {f2bf(v.x), f2bf(v.y), f2bf(v.z), f2bf(v.w)};
            *(uint2*)&drow[e * 4] = *(uint2*)o;
        }
        return;
    }
    if (bid < SEG_GTXT) {  // W2 transpose+convert
        int idx = (bid - SEG_W2T) * 256 + t;  // 524288
        int k = idx >> 8, n = idx & 255;
        W2t[(size_t)n * 2048 + k] = f2bf(W2[idx]);
        return;
    }
    if (bid < SEG_W1T) {  // gather text rows (4 per block)
        int base = (bid - SEG_GTXT) * 4;
#pragma unroll
        for (int i0 = 0; i0 < 2; i0++) {
            int i = i0 * 256 + t;  // 4 rows x 96 float4 = 384
            if (i < 384) {
                int rr = i / 96, c4 = i % 96;
                int r = base + rr;
                const float4* s4 = (const float4*)(text_table + (size_t)rel[r] * 384);
                float4 v = s4[c4];
                u16 o[4] = {f2bf(v.x), f2bf(v.y), f2bf(v.z), f2bf(v.w)};
                *(uint2*)&Atx[(size_t)r * 384 + c4 * 4] = *(uint2*)o;
            }
        }
        return;
    }
    if (bid < SEG_WTAIL) {  // W1 transpose+convert
        int idx = (bid - SEG_W1T) * 256 + t;  // 98304
        int k = idx >> 8, n = idx & 255;
        W1t[(size_t)n * 384 + k] = f2bf(W1[idx]);
        return;
    }
    if (bid < SEG_W3C) {  // tail weights c-major bf16: [Wq|Wk|Wv|Wo|Wd]
        int idx = (bid - SEG_WTAIL) * 256 + t;  // 737280
        int w = idx / 147456;
        int rem = idx - w * 147456;
        int k = rem / 384, c = rem - k * 384;
        const float* S = (w == 0) ? Wq : (w == 1) ? Wk : (w == 2) ? Wv : (w == 3) ? Wo : Wd;
        Wtail[(size_t)w * 147456 + (size_t)c * 384 + k] = f2bf(S[rem]);
        return;
    }
    if (bid < SEG_PE) {  // W3 c-major bf16
        int idx = (bid - SEG_W3C) * 256 + t;  // 294912
        int k = idx / 384, c = idx - k * 384;
        W3c[(size_t)c * 768 + k] = f2bf(W3[idx]);
        return;
    }
    if (bid < SEG_CNT) {  // PE table
        int idx = (bid - SEG_PE) * 256 + t;  // 76800
        int l = idx / Dn, c = idx % Dn;
        float v = 0.f;
        if (l > 0) {
            int j2 = c >> 1;
            float div = expf(-0.07195578415606394f * (float)j2);
            float ang = (float)(l - 1) * div;
            v = 0.002f * ((c & 1) ? cosf(ang) : sinf(ang));
        }
        pe_tab[idx] = v;
        return;
    }
    {  // degree count
        int k = (bid - SEG_CNT) * 256 + t;
        if (k < NNZn) {
            atomicAdd(&cnt_e[edge_idx[k]], 1);
            atomicAdd(&cnt_n[node_idx[k]], 1);
        }
    }
}

__global__ void fill_csr(const int* __restrict__ node_idx, const int* __restrict__ edge_idx,
                         const int* __restrict__ off_e, const int* __restrict__ off_n,
                         int* __restrict__ cur_e, int* __restrict__ cur_n,
                         int* __restrict__ memb_e, int* __restrict__ memb_n, int nnz) {
    int k = blockIdx.x * blockDim.x + threadIdx.x;
    if (k < nnz) {
        int n = node_idx[k], ed = edge_idx[k];
        int pe = atomicAdd(&cur_e[ed], 1);
        memb_e[off_e[ed] + pe] = n;
        int pn = atomicAdd(&cur_n[n], 1);
        memb_n[off_n[n] + pn] = ed;
    }
}

// ---------------- MFMA projection GEMM (+ CSR offs blocks at y>=300) ----------------
// A is pre-gathered packed bf16. y<150 -> img tile (K=2048, LPT-first);
// 150<=y<300 -> text tile; y>=300 -> offs/inv computation (unordered buckets).
#define LOFF(row, kc) (((row) << 6) + ((((kc) ^ ((row) & 7))) << 3))

__global__ __launch_bounds__(256) void gemm_offs(
    const u16* __restrict__ Atx, const u16* __restrict__ Aim,
    const u16* __restrict__ W1t, const u16* __restrict__ W2t,
    const float* __restrict__ b1, const float* __restrict__ b2,
    const float* __restrict__ pe_tab, u16* __restrict__ xg,
    const int* __restrict__ cnt_e, const int* __restrict__ cnt_n,
    int* __restrict__ off_e, int* __restrict__ off_n,
    float* __restrict__ invE, float* __restrict__ invN, int* __restrict__ cursors) {
    __shared__ u16 As[64 * 64];
    __shared__ u16 Bs[256 * 64];
    const int tid = threadIdx.x;
    const int yy = blockIdx.y;
    if (yy >= 300) {  // CSR offsets (independent work)
        int i = (yy - 300) * 256 + tid;
        if (i < En) {
            int c = cnt_e[i];
            off_e[i] = atomicAdd(&cursors[0], c);
            invE[i] = 1.f / fmaxf((float)c, 1.f);
        }
        if (i < Nn) {
            int c = cnt_n[i];
            off_n[i] = atomicAdd(&cursors[1], c);
            invN[i] = 1.f / fmaxf((float)c, 1.f);
        }
        return;
    }
    const int lane = tid & 63;
    const int wv = tid >> 6;
    const int z = (yy < 150) ? 1 : 0;
    const int m0 = ((yy < 150) ? yy : yy - 150) * 64;
    const int K = z ? 2048 : 384;
    const u16* A = z ? Aim : Atx;
    const u16* Bt = z ? W2t : W1t;
    const float* bias = z ? b2 : b1;
    const int coloff = z ? 256 : 0;

    const int srow = tid >> 3;  // 0..31
    const int skc = tid & 7;    // 0..7
    const u16* ap0 = A + (size_t)(m0 + srow) * K + skc * 8;
    const u16* ap1 = A + (size_t)(m0 + srow + 32) * K + skc * 8;
    const u16* bp = Bt + (size_t)srow * K + skc * 8;

    f32x4 acc[4][4] = {};
    uint4 rA0, rA1, rB[8];

    rA0 = *(const uint4*)(ap0);
    rA1 = *(const uint4*)(ap1);
#pragma unroll
    for (int it = 0; it < 8; it++) rB[it] = *(const uint4*)(bp + (size_t)(it * 32) * K);

    for (int k0 = 0; k0 < K; k0 += 64) {
        *(uint4*)&As[LOFF(srow, skc)] = rA0;
        *(uint4*)&As[LOFF(srow + 32, skc)] = rA1;
#pragma unroll
        for (int it = 0; it < 8; it++) *(uint4*)&Bs[LOFF(it * 32 + srow, skc)] = rB[it];
        __syncthreads();
        int kn = k0 + 64;
        if (kn < K) {
            rA0 = *(const uint4*)(ap0 + kn);
            rA1 = *(const uint4*)(ap1 + kn);
#pragma unroll
            for (int it = 0; it < 8; it++)
                rB[it] = *(const uint4*)(bp + (size_t)(it * 32) * K + kn);
        }
#pragma unroll
        for (int ks = 0; ks < 2; ks++) {
            int kc = ks * 4 + (lane >> 4);
            bf16x8 a[4], b[4];
#pragma unroll
            for (int mf = 0; mf < 4; mf++) a[mf] = *(bf16x8*)&As[LOFF(mf * 16 + (lane & 15), kc)];
#pragma unroll
            for (int nf = 0; nf < 4; nf++)
                b[nf] = *(bf16x8*)&Bs[LOFF(wv * 64 + nf * 16 + (lane & 15), kc)];
#pragma unroll
            for (int mf = 0; mf < 4; mf++)
#pragma unroll
                for (int nf = 0; nf < 4; nf++)
                    acc[mf][nf] = __builtin_amdgcn_mfma_f32_16x16x32_bf16(a[mf], b[nf], acc[mf][nf], 0, 0, 0);
        }
        __syncthreads();
    }

#pragma unroll
    for (int mf = 0; mf < 4; mf++) {
#pragma unroll
        for (int nf = 0; nf < 4; nf++) {
#pragma unroll
            for (int r = 0; r < 4; r++) {
                int row = m0 + mf * 16 + (lane >> 4) * 4 + r;
                int col = wv * 64 + nf * 16 + (lane & 15);
                float v = acc[mf][nf][r] + bias[col] + pe_tab[(row % Ln) * Dn + col];
                xg[(size_t)row * PK + coloff + col] = f2bf(v);
            }
        }
    }
}

// ---------------- packed aggregation (shfl-batched member indices) ----------------
__global__ __launch_bounds__(256) void agg_kernel(
    const u16* __restrict__ src, u16* __restrict__ dst,
    const int* __restrict__ memb, const int* __restrict__ off,
    const int* __restrict__ cnt, const float* __restrict__ inv, int nrows) {
    int row = blockIdx.x * 4 + (threadIdx.x >> 6);
    int lane = threadIdx.x & 63;
    if (row >= nrows) return;
    int s = off[row], tot = cnt[row];
    float acc[8] = {};
    const u16* base = src + (size_t)lane * 8;
    for (int cb = 0; cb < tot; cb += 64) {
        int m = min(64, tot - cb);
        int my = (lane < m) ? memb[s + cb + lane] : 0;
        for (int j = 0; j < m; j++) {
            int r = __builtin_amdgcn_readfirstlane(__shfl(my, j));
            uint4 v = *(const uint4*)(base + (size_t)r * PK);
            u16 h[8];
            *(uint4*)h = v;
#pragma unroll
            for (int q = 0; q < 8; q++) acc[q] += bf2f(h[q]);
        }
    }
    float sc = inv[row];
    u16 o[8];
#pragma unroll
    for (int j = 0; j < 8; j++) o[j] = f2bf(acc[j] * sc);
    *(uint4*)(dst + (size_t)row * PK + lane * 8) = *(uint4*)o;
}

// ---------------- fused tail (768 threads, c-major bf16 weights) ----------------
__global__ __launch_bounds__(768) void tail_all(
    const u16* __restrict__ zg, const u16* __restrict__ W12c,
    const float* __restrict__ bias12, const float* __restrict__ bias2w,
    const int* __restrict__ off_e, const int* __restrict__ cnt_e, const int* __restrict__ memb_e,
    const int* __restrict__ off_n, const int* __restrict__ cnt_n, const int* __restrict__ memb_n,
    const float* __restrict__ invE, const float* __restrict__ invN,
    const float* __restrict__ ut, const int* __restrict__ uid,
    const u16* __restrict__ W3c, const float* __restrict__ b3,
    const u16* __restrict__ Wtail, const float* __restrict__ bd,
    const float* __restrict__ W4, const float* __restrict__ b4,
    float* __restrict__ out) {
    __shared__ float zrow[PK];
    __shared__ float psum[3][PK];
    __shared__ float kvc[768];  // [text_user 384 | img_user 384]
    __shared__ float Fv[DFn], qv[DFn];
    __shared__ float K0[DFn], K1[DFn], V0[DFn], V1[DFn], ov[DFn], o2[DFn];
    __shared__ int plist[PMAX];
    __shared__ float pw[PMAX];
    __shared__ float sarr[8], wgt[8], red[12];
    __shared__ int pcount;

    const u16* Wqc = Wtail;
    const u16* Wkc = Wtail + 147456;
    const u16* Wvc = Wtail + 294912;
    const u16* Woc = Wtail + 442368;
    const u16* Wdc = Wtail + 589824;

    int b = blockIdx.x, t = threadIdx.x;
    int r = b * Ln;
    int ns = off_n[r], ne = cnt_n[r];

    // wave 0 builds flat (node, weight) pair list for the two-hop mean
    if (t < 64) {
        int e = (t < ne) ? memb_n[ns + t] : 0;
        int es = (t < ne) ? off_e[e] : 0;
        int em = (t < ne) ? cnt_e[e] : 0;
        float w = (t < ne) ? invE[e] : 0.f;
        int pos = em;
#pragma unroll
        for (int o = 1; o < 64; o <<= 1) {
            int x = __shfl_up(pos, o);
            if (t >= o) pos += x;
        }
        int total = __shfl(pos, 63);
        pos -= em;  // exclusive prefix
        for (int j = 0; j < em; j++) {
            if (pos + j < PMAX) {
                plist[pos + j] = memb_e[es + j];
                pw[pos + j] = w;
            }
        }
        if (t == 0) pcount = min(total, PMAX);
    }
    __syncthreads();
    int P = pcount;

    // zrow = invN * sum_pairs w * zg[n] ; P split 3 ways across thread groups
    {
        int g = t >> 8;        // 0..2
        int c2 = t & 255;      // cols 2c2, 2c2+1
        float za0 = 0.f, za1 = 0.f;
        for (int i = g; i < P; i += 3) {
            int n = plist[i];
            float w = pw[i];
            u32 v = *(const u32*)&zg[(size_t)n * PK + 2 * c2];
            za0 += bf2f((u16)(v & 0xffff)) * w;
            za1 += bf2f((u16)(v >> 16)) * w;
        }
        psum[g][2 * c2] = za0;
        psum[g][2 * c2 + 1] = za1;
    }
    __syncthreads();
    if (t < PK) {
        zrow[t] = (psum[0][t] + psum[1][t] + psum[2][t]) * invN[r];
    }
    __syncthreads();

    // conv GEMV -> kvc (deg0 -> bias2w); user columns
    if (t < 512) {
        int m = t >> 8, cc = t & 255;
        float acc;
        if (ne == 0) {
            acc = bias2w[t];
        } else {
            acc = bias12[t];
            const u16* wp = W12c + ((size_t)m << 16) + cc * 256;
            const float* zp = zrow + m * 256;
#pragma unroll 4
            for (int k0 = 0; k0 < 256; k0 += 8) acc += dot8(wp + k0, zp + k0);
        }
        kvc[m * 384 + cc] = acc;
    } else if (t < 640) {
        int i = t - 512;
        float u = ut[(size_t)uid[b] * DUn + i];
        kvc[256 + i] = u;
        kvc[640 + i] = u;
    }
    __syncthreads();

    // F = kvc(768) @ W3 + b3
    if (t < 384) {
        float acc = b3[t];
        const u16* wp = W3c + (size_t)t * 768;
#pragma unroll 4
        for (int k0 = 0; k0 < 768; k0 += 8) acc += dot8(wp + k0, kvc + k0);
        Fv[t] = acc;
    }
    __syncthreads();

    // Q (from Fv) || K0 (from text_user)
    if (t < 384) {
        float acc = 0.f;
        const u16* wp = Wqc + (size_t)t * 384;
#pragma unroll 4
        for (int k0 = 0; k0 < 384; k0 += 8) acc += dot8(wp + k0, Fv + k0);
        qv[t] = acc;
    } else {
        int c = t - 384;
        float acc = 0.f;
        const u16* wp = Wkc + (size_t)c * 384;
#pragma unroll 4
        for (int k0 = 0; k0 < 384; k0 += 8) acc += dot8(wp + k0, kvc + k0);
        K0[c] = acc;
    }
    __syncthreads();

    // K1 (img_user) || V0 (text_user)
    if (t < 384) {
        float acc = 0.f;
        const u16* wp = Wkc + (size_t)t * 384;
#pragma unroll 4
        for (int k0 = 0; k0 < 384; k0 += 8) acc += dot8(wp + k0, kvc + 384 + k0);
        K1[t] = acc;
    } else {
        int c = t - 384;
        float acc = 0.f;
        const u16* wp = Wvc + (size_t)c * 384;
#pragma unroll 4
        for (int k0 = 0; k0 < 384; k0 += 8) acc += dot8(wp + k0, kvc + k0);
        V0[c] = acc;
    }
    __syncthreads();

    // V1 (img_user)
    if (t < 384) {
        float acc = 0.f;
        const u16* wp = Wvc + (size_t)t * 384;
#pragma unroll 4
        for (int k0 = 0; k0 < 384; k0 += 8) acc += dot8(wp + k0, kvc + 384 + k0);
        V1[t] = acc;
    }
    __syncthreads();

    // scores: 8 groups of 32 lanes (t<256): g = (head h = g>>1, kv wch = g&1)
    if (t < 256) {
        int g = t >> 5, l = t & 31;
        int h = g >> 1, wch = g & 1;
        const float* Kp = (wch ? K1 : K0) + h * 96;
        const float* qp = qv + h * 96;
        float p = 0.f;
        for (int d = l; d < 96; d += 32) p += qp[d] * Kp[d];
#pragma unroll
        for (int o = 16; o; o >>= 1) p += __shfl_down(p, o, 32);
        if (l == 0) sarr[g] = p * 0.10206207261596575f;  // 1/sqrt(96)
    }
    __syncthreads();
    if (t < 4) {
        float s0 = sarr[2 * t], s1 = sarr[2 * t + 1];
        float m = fmaxf(s0, s1);
        float e0 = expf(s0 - m), e1 = expf(s1 - m);
        float inv = 1.f / (e0 + e1);
        wgt[2 * t] = e0 * inv;
        wgt[2 * t + 1] = e1 * inv;
    }
    __syncthreads();
    if (t < 384) {
        int h = t / 96;
        ov[t] = wgt[2 * h] * V0[t] + wgt[2 * h + 1] * V1[t];
    }
    __syncthreads();
    // o2 = ov @ Wo + Fv (residual)
    if (t < 384) {
        float acc = Fv[t];
        const u16* wp = Woc + (size_t)t * 384;
#pragma unroll 4
        for (int k0 = 0; k0 < 384; k0 += 8) acc += dot8(wp + k0, ov + k0);
        o2[t] = acc;
    }
    __syncthreads();
    // o3 = relu(o2 @ Wd + bd) -> reuse qv
    if (t < 384) {
        float acc = bd[t];
        const u16* wp = Wdc + (size_t)t * 384;
#pragma unroll 4
        for (int k0 = 0; k0 < 384; k0 += 8) acc += dot8(wp + k0, o2 + k0);
        qv[t] = fmaxf(acc, 0.f);
    }
    __syncthreads();
    float p2 = (t < 384) ? qv[t] * W4[t] : 0.f;
#pragma unroll
    for (int o = 32; o; o >>= 1) p2 += __shfl_down(p2, o);
    if ((t & 63) == 0) red[t >> 6] = p2;
    __syncthreads();
    if (t == 0) {
        float s = b4[0];
#pragma unroll
        for (int i = 0; i < 12; i++) s += red[i];
        out[b] = s;
    }
}

// ---------------- launch ----------------
extern "C" void kernel_launch(void* const* d_in, const int* in_sizes, int n_in,
                              void* d_out, int out_size, void* d_ws, size_t ws_size,
                              hipStream_t stream) {
    const float* text_table = (const float*)d_in[2];
    const float* img_table  = (const float*)d_in[3];
    const float* W1 = (const float*)d_in[4];
    const float* b1 = (const float*)d_in[5];
    const float* W2 = (const float*)d_in[6];
    const float* b2 = (const float*)d_in[7];
    const float* user_table = (const float*)d_in[8];
    const float* Wt = (const float*)d_in[9];
    const float* bt = (const float*)d_in[10];
    const float* Wi = (const float*)d_in[11];
    const float* bi = (const float*)d_in[12];
    const float* Wq = (const float*)d_in[13];
    const float* Wk = (const float*)d_in[14];
    const float* Wv = (const float*)d_in[15];
    const float* Wo = (const float*)d_in[16];
    const float* W3 = (const float*)d_in[17];
    const float* b3 = (const float*)d_in[18];
    const float* Wd = (const float*)d_in[19];
    const float* bd = (const float*)d_in[20];
    const float* W4 = (const float*)d_in[21];
    const float* b4 = (const float*)d_in[22];
    const int* rel = (const int*)d_in[23];
    const int* uid = (const int*)d_in[24];
    const int* hg  = (const int*)d_in[25];
    const int* node_idx = hg;
    const int* edge_idx = hg + NNZn;

    // ---- workspace layout ----
    u16* xg  = (u16*)d_ws;              // N*PK packed [t|i]
    u16* eP  = xg + NPl;                // E*PK
    u16* zg  = eP + EPl;                // N*PK
    u16* Atx = zg + NPl;                // N*384 gathered text (bf16)
    u16* Aim = Atx + (size_t)Nn * 384;  // N*2048 gathered img (bf16)
    u16* W1t = Aim + (size_t)Nn * 2048; // 256*384
    u16* W2t = W1t + 98304;             // 256*2048
    u16* W12c = W2t + 524288;           // 2*256*256 (c-major)
    u16* Wtail = W12c + 131072;         // 5*384*384 (c-major)
    u16* W3c = Wtail + 737280;          // 768*384 -> [c][k]
    float* invE   = (float*)(W3c + 294912);      // E
    float* invN   = invE + En;          // N
    float* pe_tab = invN + Nn;          // L*D
    float* bias12 = pe_tab + Ln * Dn;   // 2*256
    float* bias2w = bias12 + 512;       // 2*256
    int* cnt_e  = (int*)(bias2w + 512); // E      -- zeroed region start
    int* cnt_n  = cnt_e + En;           // N
    int* cur_e  = cnt_n + Nn;           // E
    int* cur_n  = cur_e + En;           // N
    int* cursors = cur_n + Nn;          // 2      -- zeroed region end
    int* off_e  = cursors + 2;          // E
    int* off_n  = off_e + En;           // N
    int* memb_e = off_n + Nn;           // NNZ
    int* memb_n = memb_e + NNZn;        // NNZ
    float* outp = (float*)d_out;

    // 0. zero counters/cursors
    hipMemsetAsync(cnt_e, 0, (size_t)(2 * (En + Nn) + 2) * sizeof(int), stream);
    // 1. fused prologue
    prep_all<<<SEG_END, 256, 0, stream>>>(pe_tab, W1, W1t, W2, W2t, Wt, bt, Wi, bi,
                                          W12c, bias12, bias2w, node_idx, edge_idx,
                                          cnt_e, cnt_n, text_table, img_table, rel,
                                          Atx, Aim, Wq, Wk, Wv, Wo, Wd, Wtail, W3, W3c);
    // 2. projections (img first for LPT) + CSR offsets (blocks y>=300)
    dim3 grdP(1, 338, 1);
    gemm_offs<<<grdP, 256, 0, stream>>>(Atx, Aim, W1t, W2t, b1, b2, pe_tab, xg,
                                        cnt_e, cnt_n, off_e, off_n, invE, invN, cursors);
    // 3. CSR fill
    fill_csr<<<(NNZn + 255) / 256, 256, 0, stream>>>(node_idx, edge_idx, off_e, off_n,
                                                     cur_e, cur_n, memb_e, memb_n, NNZn);
    // 4-5. first aggregation round: zg = A xg
    agg_kernel<<<En / 4, 256, 0, stream>>>(xg, eP, memb_e, off_e, cnt_e, invE, En);
    agg_kernel<<<Nn / 4, 256, 0, stream>>>(eP, zg, memb_n, off_n, cnt_n, invN, Nn);
    // 6. fused tail
    tail_all<<<Bn, 768, 0, stream>>>(zg, W12c, bias12, bias2w, off_e, cnt_e, memb_e,
                                     off_n, cnt_n, memb_n, invE, invN, user_table, uid,
                                     W3c, b3, Wtail, bd, W4, b4, outp);
}

// Round 9
// 286.920 us; speedup vs baseline: 1.1484x; 1.1484x over previous
//
#include <hip/hip_runtime.h>

typedef unsigned short u16;
typedef unsigned int u32;
typedef __bf16 bf16x8 __attribute__((ext_vector_type(8)));
typedef float f32x4 __attribute__((ext_vector_type(4)));

// Problem constants
constexpr int Bn = 32, Ln = 300, Dn = 256;
constexpr int Nn = Bn * Ln;          // 9600
constexpr int En = 4000, NNZn = 100000;
constexpr int DUn = 128, DFn = 384;
constexpr int PK = 512;              // packed row: [text 256 | img 256]
constexpr long NPl = (long)Nn * PK;  // 4915200
constexpr long EPl = (long)En * PK;  // 2048000
constexpr int PMAX = 1536;           // tail pair-list capacity

// prep_all block-segment start offsets
constexpr int SEG_WPROD = 0;                   // 512
constexpr int SEG_GIMG  = SEG_WPROD + 512;     // 9600
constexpr int SEG_W2T   = SEG_GIMG + 9600;     // 2048
constexpr int SEG_GTXT  = SEG_W2T + 2048;      // 2400
constexpr int SEG_W1T   = SEG_GTXT + 2400;     // 384
constexpr int SEG_WTAIL = SEG_W1T + 384;       // 2880 (Wq,Wk,Wv,Wo,Wd c-major bf16)
constexpr int SEG_W3C   = SEG_WTAIL + 2880;    // 1152 (W3 c-major bf16)
constexpr int SEG_PE    = SEG_W3C + 1152;      // 300
constexpr int SEG_CNT   = SEG_PE + 300;        // 391
constexpr int SEG_END   = SEG_CNT + 391;

__device__ __forceinline__ u16 f2bf(float f) {
    union { float f; u32 u; } x{f};
    u32 u = x.u;
    u32 r = (u + 0x7FFFu + ((u >> 16) & 1u)) >> 16;
    return (u16)r;
}
__device__ __forceinline__ float bf2f(u16 s) {
    union { u32 u; float f; } x{(u32)s << 16};
    return x.f;
}

// dot of 8 bf16 weights (contiguous) with 8 fp32 activations (LDS)
__device__ __forceinline__ float dot8(const u16* __restrict__ w, const float* __restrict__ x) {
    uint4 v = *(const uint4*)w;
    u16 h[8];
    *(uint4*)h = v;
    float s = 0.f;
#pragma unroll
    for (int j = 0; j < 8; j++) s += x[j] * bf2f(h[j]);
    return s;
}

__device__ __forceinline__ void acc8(float* __restrict__ acc, uint4 v) {
    u16 h[8];
    *(uint4*)h = v;
#pragma unroll
    for (int q = 0; q < 8; q++) acc[q] += bf2f(h[q]);
}

// ---------------- fused prologue: all independent precompute ----------------
__global__ __launch_bounds__(256) void prep_all(
    float* __restrict__ pe_tab,
    const float* __restrict__ W1, u16* __restrict__ W1t,
    const float* __restrict__ W2, u16* __restrict__ W2t,
    const float* __restrict__ Wt, const float* __restrict__ bt,
    const float* __restrict__ Wi, const float* __restrict__ bi,
    u16* __restrict__ W12c, float* __restrict__ bias12, float* __restrict__ bias2w,
    const int* __restrict__ node_idx, const int* __restrict__ edge_idx,
    int* __restrict__ cnt_e, int* __restrict__ cnt_n,
    const float* __restrict__ text_table, const float* __restrict__ img_table,
    const int* __restrict__ rel, u16* __restrict__ Atx, u16* __restrict__ Aim,
    const float* __restrict__ Wq, const float* __restrict__ Wk,
    const float* __restrict__ Wv, const float* __restrict__ Wo,
    const float* __restrict__ Wd, u16* __restrict__ Wtail,
    const float* __restrict__ W3, u16* __restrict__ W3c) {
    int bid = blockIdx.x;
    int t = threadIdx.x;
    if (bid < SEG_GIMG) {  // wprod: W12 = W0 @ W1 per modality, C-MAJOR bf16 out
        int idx = bid * 256 + t;  // 131072
        int m = idx >> 16;
        int k = (idx >> 8) & 255;
        int n = idx & 255;
        const float* W0 = m ? Wi : Wt;
        const float* Wl1 = W0 + 65536;
        const float* b0 = m ? bi : bt;
        float acc = 0.f;
#pragma unroll 8
        for (int j = 0; j < 256; j++) acc += W0[k * 256 + j] * Wl1[j * 256 + n];
        W12c[((size_t)m << 16) + n * 256 + k] = f2bf(acc);
        if (k == 0) {
            float ba = 0.f;
            for (int j = 0; j < 256; j++) ba += b0[j] * Wl1[j * 256 + n];
            bias12[m * 256 + n] = ba + b0[256 + n];
            bias2w[m * 256 + n] = b0[256 + n];
        }
        return;
    }
    if (bid < SEG_W2T) {  // gather img row -> packed bf16 (streaming memcpy)
        int r = bid - SEG_GIMG;
        const float4* s4 = (const float4*)(img_table + (size_t)rel[r] * 2048);
        u16* drow = Aim + (size_t)r * 2048;
#pragma unroll
        for (int i = 0; i < 2; i++) {
            int e = i * 256 + t;  // 512 float4 per row
            float4 v = s4[e];
            u16 o[4] = {f2bf(v.x), f2bf(v.y), f2bf(v.z), f2bf(v.w)};
            *(uint2*)&drow[e * 4] = *(uint2*)o;
        }
        return;
    }
    if (bid < SEG_GTXT) {  // W2 transpose+convert
        int idx = (bid - SEG_W2T) * 256 + t;  // 524288
        int k = idx >> 8, n = idx & 255;
        W2t[(size_t)n * 2048 + k] = f2bf(W2[idx]);
        return;
    }
    if (bid < SEG_W1T) {  // gather text rows (4 per block)
        int base = (bid - SEG_GTXT) * 4;
#pragma unroll
        for (int i0 = 0; i0 < 2; i0++) {
            int i = i0 * 256 + t;  // 4 rows x 96 float4 = 384
            if (i < 384) {
                int rr = i / 96, c4 = i % 96;
                int r = base + rr;
                const float4* s4 = (const float4*)(text_table + (size_t)rel[r] * 384);
                float4 v = s4[c4];
                u16 o[4] = {f2bf(v.x), f2bf(v.y), f2bf(v.z), f2bf(v.w)};
                *(uint2*)&Atx[(size_t)r * 384 + c4 * 4] = *(uint2*)o;
            }
        }
        return;
    }
    if (bid < SEG_WTAIL) {  // W1 transpose+convert
        int idx = (bid - SEG_W1T) * 256 + t;  // 98304
        int k = idx >> 8, n = idx & 255;
        W1t[(size_t)n * 384 + k] = f2bf(W1[idx]);
        return;
    }
    if (bid < SEG_W3C) {  // tail weights c-major bf16: [Wq|Wk|Wv|Wo|Wd]
        int idx = (bid - SEG_WTAIL) * 256 + t;  // 737280
        int w = idx / 147456;
        int rem = idx - w * 147456;
        int k = rem / 384, c = rem - k * 384;
        const float* S = (w == 0) ? Wq : (w == 1) ? Wk : (w == 2) ? Wv : (w == 3) ? Wo : Wd;
        Wtail[(size_t)w * 147456 + (size_t)c * 384 + k] = f2bf(S[rem]);
        return;
    }
    if (bid < SEG_PE) {  // W3 c-major bf16
        int idx = (bid - SEG_W3C) * 256 + t;  // 294912
        int k = idx / 384, c = idx - k * 384;
        W3c[(size_t)c * 768 + k] = f2bf(W3[idx]);
        return;
    }
    if (bid < SEG_CNT) {  // PE table
        int idx = (bid - SEG_PE) * 256 + t;  // 76800
        int l = idx / Dn, c = idx % Dn;
        float v = 0.f;
        if (l > 0) {
            int j2 = c >> 1;
            float div = expf(-0.07195578415606394f * (float)j2);
            float ang = (float)(l - 1) * div;
            v = 0.002f * ((c & 1) ? cosf(ang) : sinf(ang));
        }
        pe_tab[idx] = v;
        return;
    }
    {  // degree count
        int k = (bid - SEG_CNT) * 256 + t;
        if (k < NNZn) {
            atomicAdd(&cnt_e[edge_idx[k]], 1);
            atomicAdd(&cnt_n[node_idx[k]], 1);
        }
    }
}

__global__ void fill_csr(const int* __restrict__ node_idx, const int* __restrict__ edge_idx,
                         const int* __restrict__ off_e, const int* __restrict__ off_n,
                         int* __restrict__ cur_e, int* __restrict__ cur_n,
                         int* __restrict__ memb_e, int* __restrict__ memb_n, int nnz) {
    int k = blockIdx.x * blockDim.x + threadIdx.x;
    if (k < nnz) {
        int n = node_idx[k], ed = edge_idx[k];
        int pe = atomicAdd(&cur_e[ed], 1);
        memb_e[off_e[ed] + pe] = n;
        int pn = atomicAdd(&cur_n[n], 1);
        memb_n[off_n[n] + pn] = ed;
    }
}

// ---------------- MFMA projection GEMM (+ CSR offs blocks at y>=300) ----------------
#define LOFF(row, kc) (((row) << 6) + ((((kc) ^ ((row) & 7))) << 3))

__global__ __launch_bounds__(256) void gemm_offs(
    const u16* __restrict__ Atx, const u16* __restrict__ Aim,
    const u16* __restrict__ W1t, const u16* __restrict__ W2t,
    const float* __restrict__ b1, const float* __restrict__ b2,
    const float* __restrict__ pe_tab, u16* __restrict__ xg,
    const int* __restrict__ cnt_e, const int* __restrict__ cnt_n,
    int* __restrict__ off_e, int* __restrict__ off_n,
    float* __restrict__ invE, float* __restrict__ invN, int* __restrict__ cursors) {
    __shared__ u16 As[64 * 64];
    __shared__ u16 Bs[256 * 64];
    const int tid = threadIdx.x;
    const int yy = blockIdx.y;
    if (yy >= 300) {  // CSR offsets (independent work; unordered buckets)
        int i = (yy - 300) * 256 + tid;
        if (i < En) {
            int c = cnt_e[i];
            off_e[i] = atomicAdd(&cursors[0], c);
            invE[i] = 1.f / fmaxf((float)c, 1.f);
        }
        if (i < Nn) {
            int c = cnt_n[i];
            off_n[i] = atomicAdd(&cursors[1], c);
            invN[i] = 1.f / fmaxf((float)c, 1.f);
        }
        return;
    }
    const int lane = tid & 63;
    const int wv = tid >> 6;
    const int z = (yy < 150) ? 1 : 0;
    const int m0 = ((yy < 150) ? yy : yy - 150) * 64;
    const int K = z ? 2048 : 384;
    const u16* A = z ? Aim : Atx;
    const u16* Bt = z ? W2t : W1t;
    const float* bias = z ? b2 : b1;
    const int coloff = z ? 256 : 0;

    const int srow = tid >> 3;  // 0..31
    const int skc = tid & 7;    // 0..7
    const u16* ap0 = A + (size_t)(m0 + srow) * K + skc * 8;
    const u16* ap1 = A + (size_t)(m0 + srow + 32) * K + skc * 8;
    const u16* bp = Bt + (size_t)srow * K + skc * 8;

    f32x4 acc[4][4] = {};
    uint4 rA0, rA1, rB[8];

    rA0 = *(const uint4*)(ap0);
    rA1 = *(const uint4*)(ap1);
#pragma unroll
    for (int it = 0; it < 8; it++) rB[it] = *(const uint4*)(bp + (size_t)(it * 32) * K);

    for (int k0 = 0; k0 < K; k0 += 64) {
        *(uint4*)&As[LOFF(srow, skc)] = rA0;
        *(uint4*)&As[LOFF(srow + 32, skc)] = rA1;
#pragma unroll
        for (int it = 0; it < 8; it++) *(uint4*)&Bs[LOFF(it * 32 + srow, skc)] = rB[it];
        __syncthreads();
        int kn = k0 + 64;
        if (kn < K) {
            rA0 = *(const uint4*)(ap0 + kn);
            rA1 = *(const uint4*)(ap1 + kn);
#pragma unroll
            for (int it = 0; it < 8; it++)
                rB[it] = *(const uint4*)(bp + (size_t)(it * 32) * K + kn);
        }
#pragma unroll
        for (int ks = 0; ks < 2; ks++) {
            int kc = ks * 4 + (lane >> 4);
            bf16x8 a[4], b[4];
#pragma unroll
            for (int mf = 0; mf < 4; mf++) a[mf] = *(bf16x8*)&As[LOFF(mf * 16 + (lane & 15), kc)];
#pragma unroll
            for (int nf = 0; nf < 4; nf++)
                b[nf] = *(bf16x8*)&Bs[LOFF(wv * 64 + nf * 16 + (lane & 15), kc)];
#pragma unroll
            for (int mf = 0; mf < 4; mf++)
#pragma unroll
                for (int nf = 0; nf < 4; nf++)
                    acc[mf][nf] = __builtin_amdgcn_mfma_f32_16x16x32_bf16(a[mf], b[nf], acc[mf][nf], 0, 0, 0);
        }
        __syncthreads();
    }

#pragma unroll
    for (int mf = 0; mf < 4; mf++) {
#pragma unroll
        for (int nf = 0; nf < 4; nf++) {
#pragma unroll
            for (int r = 0; r < 4; r++) {
                int row = m0 + mf * 16 + (lane >> 4) * 4 + r;
                int col = wv * 64 + nf * 16 + (lane & 15);
                float v = acc[mf][nf][r] + bias[col] + pe_tab[(row % Ln) * Dn + col];
                xg[(size_t)row * PK + coloff + col] = f2bf(v);
            }
        }
    }
}

// ---------------- packed aggregation (4 independent row-loads in flight) ----------------
__global__ __launch_bounds__(256) void agg_kernel(
    const u16* __restrict__ src, u16* __restrict__ dst,
    const int* __restrict__ memb, const int* __restrict__ off,
    const int* __restrict__ cnt, const float* __restrict__ inv, int nrows) {
    int row = blockIdx.x * 4 + (threadIdx.x >> 6);
    int lane = threadIdx.x & 63;
    if (row >= nrows) return;
    int s = off[row], tot = cnt[row];
    float acc[8] = {};
    const u16* base = src + (size_t)lane * 8;
    for (int cb = 0; cb < tot; cb += 64) {
        int m = min(64, tot - cb);
        int my = (lane < m) ? memb[s + cb + lane] : 0;
        int j = 0;
        for (; j + 4 <= m; j += 4) {
            int r0 = __builtin_amdgcn_readfirstlane(__shfl(my, j));
            int r1 = __builtin_amdgcn_readfirstlane(__shfl(my, j + 1));
            int r2 = __builtin_amdgcn_readfirstlane(__shfl(my, j + 2));
            int r3 = __builtin_amdgcn_readfirstlane(__shfl(my, j + 3));
            uint4 v0 = *(const uint4*)(base + (size_t)r0 * PK);
            uint4 v1 = *(const uint4*)(base + (size_t)r1 * PK);
            uint4 v2 = *(const uint4*)(base + (size_t)r2 * PK);
            uint4 v3 = *(const uint4*)(base + (size_t)r3 * PK);
            acc8(acc, v0);
            acc8(acc, v1);
            acc8(acc, v2);
            acc8(acc, v3);
        }
        for (; j < m; j++) {
            int r = __builtin_amdgcn_readfirstlane(__shfl(my, j));
            acc8(acc, *(const uint4*)(base + (size_t)r * PK));
        }
    }
    float sc = inv[row];
    u16 o[8];
#pragma unroll
    for (int j = 0; j < 8; j++) o[j] = f2bf(acc[j] * sc);
    *(uint4*)(dst + (size_t)row * PK + lane * 8) = *(uint4*)o;
}

// ---------------- fused tail (768 threads; cooperative pair expansion) ----------------
__global__ __launch_bounds__(768) void tail_all(
    const u16* __restrict__ zg, const u16* __restrict__ W12c,
    const float* __restrict__ bias12, const float* __restrict__ bias2w,
    const int* __restrict__ off_e, const int* __restrict__ cnt_e, const int* __restrict__ memb_e,
    const int* __restrict__ off_n, const int* __restrict__ cnt_n, const int* __restrict__ memb_n,
    const float* __restrict__ invE, const float* __restrict__ invN,
    const float* __restrict__ ut, const int* __restrict__ uid,
    const u16* __restrict__ W3c, const float* __restrict__ b3,
    const u16* __restrict__ Wtail, const float* __restrict__ bd,
    const float* __restrict__ W4, const float* __restrict__ b4,
    float* __restrict__ out) {
    __shared__ float zrow[PK];
    __shared__ float psum[3][PK];
    __shared__ float kvc[768];  // [text_user 384 | img_user 384]
    __shared__ float Fv[DFn], qv[DFn];
    __shared__ float K0[DFn], K1[DFn], V0[DFn], V1[DFn], ov[DFn], o2[DFn];
    __shared__ int plist[PMAX];
    __shared__ float pw[PMAX];
    __shared__ int ecum[64], epos[64], ees[64];
    __shared__ float ew[64];
    __shared__ float sarr[8], wgt[8], red[12];
    __shared__ int pcount;

    const u16* Wqc = Wtail;
    const u16* Wkc = Wtail + 147456;
    const u16* Wvc = Wtail + 294912;
    const u16* Woc = Wtail + 442368;
    const u16* Wdc = Wtail + 589824;

    int b = blockIdx.x, t = threadIdx.x;
    int r = b * Ln;
    int ns = off_n[r], ne = cnt_n[r];

    // wave 0: load-free edge-extent scan (ne <= 64 edges)
    if (t < 64) {
        int e = (t < ne) ? memb_n[ns + t] : 0;
        int es = (t < ne) ? off_e[e] : 0;
        int em = (t < ne) ? cnt_e[e] : 0;
        float w = (t < ne) ? invE[e] : 0.f;
        int pos = em;
#pragma unroll
        for (int o = 1; o < 64; o <<= 1) {
            int x = __shfl_up(pos, o);
            if (t >= o) pos += x;
        }
        ecum[t] = pos;            // inclusive prefix
        epos[t] = pos - em;       // exclusive prefix
        ees[t] = es;
        ew[t] = w;
        if (t == 63) pcount = min(pos, PMAX);
    }
    __syncthreads();
    int P = pcount;

    // cooperative pair expansion: one global load per thread (binary search in LDS)
    for (int i = t; i < P; i += 768) {
        int L = 0;  // count of lanes with ecum <= i
#pragma unroll
        for (int step = 32; step; step >>= 1)
            if (L + step <= 64 && ecum[L + step - 1] <= i) L += step;
        int j = i - epos[L];
        plist[i] = memb_e[ees[L] + j];
        pw[i] = ew[L];
    }
    __syncthreads();

    // zrow = invN * sum_pairs w * zg[n] ; P split 3 ways across thread groups
    {
        int g = t >> 8;        // 0..2
        int c2 = t & 255;      // cols 2c2, 2c2+1
        float za0 = 0.f, za1 = 0.f;
#pragma unroll 4
        for (int i = g; i < P; i += 3) {
            int n = plist[i];
            float w = pw[i];
            u32 v = *(const u32*)&zg[(size_t)n * PK + 2 * c2];
            za0 += bf2f((u16)(v & 0xffff)) * w;
            za1 += bf2f((u16)(v >> 16)) * w;
        }
        psum[g][2 * c2] = za0;
        psum[g][2 * c2 + 1] = za1;
    }
    __syncthreads();
    if (t < PK) {
        zrow[t] = (psum[0][t] + psum[1][t] + psum[2][t]) * invN[r];
    }
    __syncthreads();

    // conv GEMV -> kvc (deg0 -> bias2w); user columns
    if (t < 512) {
        int m = t >> 8, cc = t & 255;
        float acc;
        if (ne == 0) {
            acc = bias2w[t];
        } else {
            acc = bias12[t];
            const u16* wp = W12c + ((size_t)m << 16) + cc * 256;
            const float* zp = zrow + m * 256;
#pragma unroll 4
            for (int k0 = 0; k0 < 256; k0 += 8) acc += dot8(wp + k0, zp + k0);
        }
        kvc[m * 384 + cc] = acc;
    } else if (t < 640) {
        int i = t - 512;
        float u = ut[(size_t)uid[b] * DUn + i];
        kvc[256 + i] = u;
        kvc[640 + i] = u;
    }
    __syncthreads();

    // F = kvc(768) @ W3 + b3
    if (t < 384) {
        float acc = b3[t];
        const u16* wp = W3c + (size_t)t * 768;
#pragma unroll 4
        for (int k0 = 0; k0 < 768; k0 += 8) acc += dot8(wp + k0, kvc + k0);
        Fv[t] = acc;
    }
    __syncthreads();

    // Q (from Fv) || K0 (from text_user)
    if (t < 384) {
        float acc = 0.f;
        const u16* wp = Wqc + (size_t)t * 384;
#pragma unroll 4
        for (int k0 = 0; k0 < 384; k0 += 8) acc += dot8(wp + k0, Fv + k0);
        qv[t] = acc;
    } else {
        int c = t - 384;
        float acc = 0.f;
        const u16* wp = Wkc + (size_t)c * 384;
#pragma unroll 4
        for (int k0 = 0; k0 < 384; k0 += 8) acc += dot8(wp + k0, kvc + k0);
        K0[c] = acc;
    }
    __syncthreads();

    // K1 (img_user) || V0 (text_user)
    if (t < 384) {
        float acc = 0.f;
        const u16* wp = Wkc + (size_t)t * 384;
#pragma unroll 4
        for (int k0 = 0; k0 < 384; k0 += 8) acc += dot8(wp + k0, kvc + 384 + k0);
        K1[t] = acc;
    } else {
        int c = t - 384;
        float acc = 0.f;
        const u16* wp = Wvc + (size_t)c * 384;
#pragma unroll 4
        for (int k0 = 0; k0 < 384; k0 += 8) acc += dot8(wp + k0, kvc + k0);
        V0[c] = acc;
    }
    __syncthreads();

    // V1 (img_user)
    if (t < 384) {
        float acc = 0.f;
        const u16* wp = Wvc + (size_t)t * 384;
#pragma unroll 4
        for (int k0 = 0; k0 < 384; k0 += 8) acc += dot8(wp + k0, kvc + 384 + k0);
        V1[t] = acc;
    }
    __syncthreads();

    // scores: 8 groups of 32 lanes (t<256): g = (head h = g>>1, kv wch = g&1)
    if (t < 256) {
        int g = t >> 5, l = t & 31;
        int h = g >> 1, wch = g & 1;
        const float* Kp = (wch ? K1 : K0) + h * 96;
        const float* qp = qv + h * 96;
        float p = 0.f;
        for (int d = l; d < 96; d += 32) p += qp[d] * Kp[d];
#pragma unroll
        for (int o = 16; o; o >>= 1) p += __shfl_down(p, o, 32);
        if (l == 0) sarr[g] = p * 0.10206207261596575f;  // 1/sqrt(96)
    }
    __syncthreads();
    if (t < 4) {
        float s0 = sarr[2 * t], s1 = sarr[2 * t + 1];
        float m = fmaxf(s0, s1);
        float e0 = expf(s0 - m), e1 = expf(s1 - m);
        float inv = 1.f / (e0 + e1);
        wgt[2 * t] = e0 * inv;
        wgt[2 * t + 1] = e1 * inv;
    }
    __syncthreads();
    if (t < 384) {
        int h = t / 96;
        ov[t] = wgt[2 * h] * V0[t] + wgt[2 * h + 1] * V1[t];
    }
    __syncthreads();
    // o2 = ov @ Wo + Fv (residual)
    if (t < 384) {
        float acc = Fv[t];
        const u16* wp = Woc + (size_t)t * 384;
#pragma unroll 4
        for (int k0 = 0; k0 < 384; k0 += 8) acc += dot8(wp + k0, ov + k0);
        o2[t] = acc;
    }
    __syncthreads();
    // o3 = relu(o2 @ Wd + bd) -> reuse qv
    if (t < 384) {
        float acc = bd[t];
        const u16* wp = Wdc + (size_t)t * 384;
#pragma unroll 4
        for (int k0 = 0; k0 < 384; k0 += 8) acc += dot8(wp + k0, o2 + k0);
        qv[t] = fmaxf(acc, 0.f);
    }
    __syncthreads();
    float p2 = (t < 384) ? qv[t] * W4[t] : 0.f;
#pragma unroll
    for (int o = 32; o; o >>= 1) p2 += __shfl_down(p2, o);
    if ((t & 63) == 0) red[t >> 6] = p2;
    __syncthreads();
    if (t == 0) {
        float s = b4[0];
#pragma unroll
        for (int i = 0; i < 12; i++) s += red[i];
        out[b] = s;
    }
}

// ---------------- launch ----------------
extern "C" void kernel_launch(void* const* d_in, const int* in_sizes, int n_in,
                              void* d_out, int out_size, void* d_ws, size_t ws_size,
                              hipStream_t stream) {
    const float* text_table = (const float*)d_in[2];
    const float* img_table  = (const float*)d_in[3];
    const float* W1 = (const float*)d_in[4];
    const float* b1 = (const float*)d_in[5];
    const float* W2 = (const float*)d_in[6];
    const float* b2 = (const float*)d_in[7];
    const float* user_table = (const float*)d_in[8];
    const float* Wt = (const float*)d_in[9];
    const float* bt = (const float*)d_in[10];
    const float* Wi = (const float*)d_in[11];
    const float* bi = (const float*)d_in[12];
    const float* Wq = (const float*)d_in[13];
    const float* Wk = (const float*)d_in[14];
    const float* Wv = (const float*)d_in[15];
    const float* Wo = (const float*)d_in[16];
    const float* W3 = (const float*)d_in[17];
    const float* b3 = (const float*)d_in[18];
    const float* Wd = (const float*)d_in[19];
    const float* bd = (const float*)d_in[20];
    const float* W4 = (const float*)d_in[21];
    const float* b4 = (const float*)d_in[22];
    const int* rel = (const int*)d_in[23];
    const int* uid = (const int*)d_in[24];
    const int* hg  = (const int*)d_in[25];
    const int* node_idx = hg;
    const int* edge_idx = hg + NNZn;

    // ---- workspace layout ----
    u16* xg  = (u16*)d_ws;              // N*PK packed [t|i]
    u16* eP  = xg + NPl;                // E*PK
    u16* zg  = eP + EPl;                // N*PK
    u16* Atx = zg + NPl;                // N*384 gathered text (bf16)
    u16* Aim = Atx + (size_t)Nn * 384;  // N*2048 gathered img (bf16)
    u16* W1t = Aim + (size_t)Nn * 2048; // 256*384
    u16* W2t = W1t + 98304;             // 256*2048
    u16* W12c = W2t + 524288;           // 2*256*256 (c-major)
    u16* Wtail = W12c + 131072;         // 5*384*384 (c-major)
    u16* W3c = Wtail + 737280;          // 768*384 -> [c][k]
    float* invE   = (float*)(W3c + 294912);      // E
    float* invN   = invE + En;          // N
    float* pe_tab = invN + Nn;          // L*D
    float* bias12 = pe_tab + Ln * Dn;   // 2*256
    float* bias2w = bias12 + 512;       // 2*256
    int* cnt_e  = (int*)(bias2w + 512); // E      -- zeroed region start
    int* cnt_n  = cnt_e + En;           // N
    int* cur_e  = cnt_n + Nn;           // E
    int* cur_n  = cur_e + En;           // N
    int* cursors = cur_n + Nn;          // 2      -- zeroed region end
    int* off_e  = cursors + 2;          // E
    int* off_n  = off_e + En;           // N
    int* memb_e = off_n + Nn;           // NNZ
    int* memb_n = memb_e + NNZn;        // NNZ
    float* outp = (float*)d_out;

    // 0. zero counters/cursors
    hipMemsetAsync(cnt_e, 0, (size_t)(2 * (En + Nn) + 2) * sizeof(int), stream);
    // 1. fused prologue
    prep_all<<<SEG_END, 256, 0, stream>>>(pe_tab, W1, W1t, W2, W2t, Wt, bt, Wi, bi,
                                          W12c, bias12, bias2w, node_idx, edge_idx,
                                          cnt_e, cnt_n, text_table, img_table, rel,
                                          Atx, Aim, Wq, Wk, Wv, Wo, Wd, Wtail, W3, W3c);
    // 2. projections (img first for LPT) + CSR offsets (blocks y>=300)
    dim3 grdP(1, 338, 1);
    gemm_offs<<<grdP, 256, 0, stream>>>(Atx, Aim, W1t, W2t, b1, b2, pe_tab, xg,
                                        cnt_e, cnt_n, off_e, off_n, invE, invN, cursors);
    // 3. CSR fill
    fill_csr<<<(NNZn + 255) / 256, 256, 0, stream>>>(node_idx, edge_idx, off_e, off_n,
                                                     cur_e, cur_n, memb_e, memb_n, NNZn);
    // 4-5. first aggregation round: zg = A xg
    agg_kernel<<<En / 4, 256, 0, stream>>>(xg, eP, memb_e, off_e, cnt_e, invE, En);
    agg_kernel<<<Nn / 4, 256, 0, stream>>>(eP, zg, memb_n, off_n, cnt_n, invN, Nn);
    // 6. fused tail
    tail_all<<<Bn, 768, 0, stream>>>(zg, W12c, bias12, bias2w, off_e, cnt_e, memb_e,
                                     off_n, cnt_n, memb_n, invE, invN, user_table, uid,
                                     W3c, b3, Wtail, bd, W4, b4, outp);
}